// Round 1
// baseline (113.827 us; speedup 1.0000x reference)
//
#include <hip/hip_runtime.h>

#define BB 4
#define NN 512
#define EE 256
#define HH 8
#define DD 32
#define SCALING 0.17677669529663687f  // 32^-0.5

// ---------------------------------------------------------------------------
// Kernel 1: Q/K projection.  Q stored [B*N, E] pre-scaled; K stored transposed
// Kt[((b*H+h)*D+d)*N + n] so the attention kernel reads it coalesced over m.
// ---------------------------------------------------------------------------
__global__ __launch_bounds__(256) void qk_proj_kernel(
    const float* __restrict__ query,
    const float* __restrict__ Wq, const float* __restrict__ bq,
    const float* __restrict__ Wk, const float* __restrict__ bk,
    float* __restrict__ Q, float* __restrict__ Kt)
{
    __shared__ float s[8][EE];
    const int row0 = blockIdx.x * 8;           // global row in [0, B*N)
    const int tid = threadIdx.x;               // output column e

    #pragma unroll
    for (int r = 0; r < 8; ++r)
        s[r][tid] = query[(row0 + r) * EE + tid];
    __syncthreads();

    float aq[8], ak[8];
    #pragma unroll
    for (int r = 0; r < 8; ++r) { aq[r] = 0.f; ak[r] = 0.f; }

    const float4* Wq4 = (const float4*)(Wq + tid * EE);
    const float4* Wk4 = (const float4*)(Wk + tid * EE);
    for (int j4 = 0; j4 < EE / 4; ++j4) {
        const float4 wq = Wq4[j4];
        const float4 wk = Wk4[j4];
        #pragma unroll
        for (int r = 0; r < 8; ++r) {
            const float4 sv = *(const float4*)&s[r][j4 * 4];
            aq[r] += sv.x * wq.x + sv.y * wq.y + sv.z * wq.z + sv.w * wq.w;
            ak[r] += sv.x * wk.x + sv.y * wk.y + sv.z * wk.z + sv.w * wk.w;
        }
    }

    const float bqv = bq[tid];
    const float bkv = bk[tid];
    const int h = tid >> 5, d = tid & 31;
    #pragma unroll
    for (int r = 0; r < 8; ++r) {
        const int grow = row0 + r;
        const int b = grow >> 9, n = grow & 511;
        Q[grow * EE + tid] = (aq[r] + bqv) * SCALING;
        Kt[((b * HH + h) * DD + d) * NN + n] = ak[r] + bkv;
    }
}

// ---------------------------------------------------------------------------
// Kernel 2: V projection folded against Wf1/2/3 -> vw[((b*H+h)*3 + c)*N + m]
// ---------------------------------------------------------------------------
__global__ __launch_bounds__(256) void vproj_kernel(
    const float* __restrict__ query,
    const float* __restrict__ Wv, const float* __restrict__ bv,
    const float* __restrict__ Wf1, const float* __restrict__ Wf2,
    const float* __restrict__ Wf3,
    float* __restrict__ vw)
{
    __shared__ float s[8][EE];
    __shared__ float sv[8][EE];
    const int row0 = blockIdx.x * 8;
    const int tid = threadIdx.x;

    #pragma unroll
    for (int r = 0; r < 8; ++r)
        s[r][tid] = query[(row0 + r) * EE + tid];
    __syncthreads();

    float av[8];
    #pragma unroll
    for (int r = 0; r < 8; ++r) av[r] = 0.f;

    const float4* Wv4 = (const float4*)(Wv + tid * EE);
    for (int j4 = 0; j4 < EE / 4; ++j4) {
        const float4 w = Wv4[j4];
        #pragma unroll
        for (int r = 0; r < 8; ++r) {
            const float4 q4 = *(const float4*)&s[r][j4 * 4];
            av[r] += q4.x * w.x + q4.y * w.y + q4.z * w.z + q4.w * w.w;
        }
    }

    const float bvv = bv[tid];
    #pragma unroll
    for (int r = 0; r < 8; ++r)
        sv[r][tid] = av[r] + bvv;
    __syncthreads();

    if (tid < 192) {
        const int r = tid / 24;
        const int rem = tid % 24;
        const int h = rem / 3;
        const int c = rem % 3;
        const float* Wf = (c == 0) ? Wf1 : ((c == 1) ? Wf2 : Wf3);
        float a = 0.f;
        #pragma unroll
        for (int d = 0; d < DD; ++d)
            a += sv[r][h * DD + d] * Wf[h * DD + d];
        const int grow = row0 + r;
        const int b = grow >> 9, m = grow & 511;
        vw[((b * HH + h) * 3 + c) * NN + m] = a;
    }
}

// ---------------------------------------------------------------------------
// Kernel 3: per (b,n): logits -> softmax -> fold vw, delta_pos, mask -> out
// ---------------------------------------------------------------------------
__global__ __launch_bounds__(512) void attn_main_kernel(
    const float* __restrict__ Q, const float* __restrict__ Kt,
    const float* __restrict__ attn_bias, const float* __restrict__ vw,
    const float* __restrict__ delta_pos,
    const int* __restrict__ drop_edge_mask, const int* __restrict__ drop_or_add,
    const float* __restrict__ bf1, const float* __restrict__ bf2,
    const float* __restrict__ bf3,
    float* __restrict__ out)
{
    const int blk = blockIdx.x;                // b*N + n
    const int b = blk >> 9, n = blk & 511;
    const int tid = threadIdx.x;               // m

    __shared__ float qs[EE];
    __shared__ float red[8];
    __shared__ float r3[3][8];

    if (tid < EE) qs[tid] = Q[blk * EE + tid];
    __syncthreads();

    float acc0 = 0.f, acc1 = 0.f, acc2 = 0.f;

    for (int h = 0; h < HH; ++h) {
        float l = attn_bias[((b * HH + h) * NN + n) * NN + tid];
        const float* kp = Kt + (b * HH + h) * DD * NN + tid;
        #pragma unroll
        for (int d = 0; d < DD; ++d)
            l += qs[h * DD + d] * kp[d * NN];

        // --- block max ---
        float v = l;
        #pragma unroll
        for (int off = 32; off; off >>= 1)
            v = fmaxf(v, __shfl_xor(v, off, 64));
        if ((tid & 63) == 0) red[tid >> 6] = v;
        __syncthreads();
        float mx = red[0];
        #pragma unroll
        for (int w = 1; w < 8; ++w) mx = fmaxf(mx, red[w]);
        __syncthreads();

        float p = __expf(l - mx);

        // --- block sum ---
        v = p;
        #pragma unroll
        for (int off = 32; off; off >>= 1)
            v += __shfl_xor(v, off, 64);
        if ((tid & 63) == 0) red[tid >> 6] = v;
        __syncthreads();
        float sum = red[0];
        #pragma unroll
        for (int w = 1; w < 8; ++w) sum += red[w];
        __syncthreads();

        p /= sum;

        const float* vwp = vw + (b * HH + h) * 3 * NN + tid;
        acc0 += p * vwp[0];
        acc1 += p * vwp[NN];
        acc2 += p * vwp[2 * NN];
    }

    float mk = 1.0f;
    if (drop_or_add[0] != 0 && drop_edge_mask[n * NN + tid] != 0) mk = 0.0f;
    const float* dp = delta_pos + ((b * NN + n) * NN + tid) * 3;
    float v0 = acc0 * dp[0] * mk;
    float v1 = acc1 * dp[1] * mk;
    float v2 = acc2 * dp[2] * mk;

    #pragma unroll
    for (int off = 32; off; off >>= 1) {
        v0 += __shfl_xor(v0, off, 64);
        v1 += __shfl_xor(v1, off, 64);
        v2 += __shfl_xor(v2, off, 64);
    }
    if ((tid & 63) == 0) {
        const int w = tid >> 6;
        r3[0][w] = v0; r3[1][w] = v1; r3[2][w] = v2;
    }
    __syncthreads();
    if (tid == 0) {
        float s0 = 0.f, s1 = 0.f, s2 = 0.f;
        #pragma unroll
        for (int w = 0; w < 8; ++w) {
            s0 += r3[0][w]; s1 += r3[1][w]; s2 += r3[2][w];
        }
        out[blk * 3 + 0] = s0 + bf1[0];
        out[blk * 3 + 1] = s1 + bf2[0];
        out[blk * 3 + 2] = s2 + bf3[0];
    }
}

// ---------------------------------------------------------------------------
extern "C" void kernel_launch(void* const* d_in, const int* in_sizes, int n_in,
                              void* d_out, int out_size, void* d_ws, size_t ws_size,
                              hipStream_t stream)
{
    const float* query          = (const float*)d_in[0];
    const float* attn_bias      = (const float*)d_in[1];
    const float* delta_pos      = (const float*)d_in[2];
    const int*   drop_edge_mask = (const int*)d_in[3];
    const float* Wq  = (const float*)d_in[4];
    const float* bq  = (const float*)d_in[5];
    const float* Wk  = (const float*)d_in[6];
    const float* bk  = (const float*)d_in[7];
    const float* Wv  = (const float*)d_in[8];
    const float* bv  = (const float*)d_in[9];
    const float* Wf1 = (const float*)d_in[10];
    const float* bf1 = (const float*)d_in[11];
    const float* Wf2 = (const float*)d_in[12];
    const float* bf2 = (const float*)d_in[13];
    const float* Wf3 = (const float*)d_in[14];
    const float* bf3 = (const float*)d_in[15];
    const int*   drop_or_add = (const int*)d_in[16];

    float* ws = (float*)d_ws;
    float* Q   = ws;                 // B*N*E   = 524288 floats
    float* Kt  = ws + 524288;        // B*H*D*N = 524288 floats
    float* vw  = ws + 1048576;       // B*H*3*N = 49152 floats

    qk_proj_kernel<<<BB * NN / 8, 256, 0, stream>>>(query, Wq, bq, Wk, bk, Q, Kt);
    vproj_kernel<<<BB * NN / 8, 256, 0, stream>>>(query, Wv, bv, Wf1, Wf2, Wf3, vw);
    attn_main_kernel<<<BB * NN, 512, 0, stream>>>(Q, Kt, attn_bias, vw, delta_pos,
                                                  drop_edge_mask, drop_or_add,
                                                  bf1, bf2, bf3, (float*)d_out);
}